// Round 6
// baseline (199.514 us; speedup 1.0000x reference)
//
#include <hip/hip_runtime.h>
#include <math.h>

typedef __attribute__((ext_vector_type(4))) float  f32x4;
typedef __attribute__((ext_vector_type(8))) short  s16x8;
typedef __attribute__((ext_vector_type(4))) short  s16x4;

#define BN_EPS 1e-3f

static constexpr int    CC    = 256;
static constexpr int    NVOX  = 32768;
static constexpr int    BATCH = 2;
static constexpr int    MTOT  = BATCH * NVOX;              // 65536 rows
static constexpr size_t ELEM_BR = (size_t)MTOT * CC;       // 16,777,216 per branch
static constexpr size_t SZ_BR   = ELEM_BR * 2;             // bf16 bytes
// workspace layout
static constexpr size_t WS_Q   = 0;
static constexpr size_t WS_K   = WS_Q  + SZ_BR;
static constexpr size_t WS_J   = WS_K  + SZ_BR;
static constexpr size_t WS_V   = WS_J  + SZ_BR;
static constexpr size_t WS_M1  = WS_V  + SZ_BR;                       // f32 [2][256][256]
static constexpr size_t WS_M2  = WS_M1 + (size_t)BATCH*CC*CC*4;
static constexpr size_t WS_AFF = WS_M2 + (size_t)BATCH*CC*CC*4;       // bf16 [2][256][256]
static constexpr size_t WS_WT  = WS_AFF + (size_t)BATCH*CC*CC*2;      // bf16 Wt[4][cout][cin]
static constexpr size_t WS_AB  = WS_WT + (size_t)4*CC*CC*2;           // f32 alpha[1024], beta[1024]

__device__ __forceinline__ short f2bf(float f) {
  union { float f; unsigned u; } v; v.f = f;
  unsigned u = v.u + 0x7FFFu + ((v.u >> 16) & 1u);   // RNE
  return (short)(u >> 16);
}

// ---------------- k0: prep — transpose weights to bf16, fold BN, zero m1/m2 ----
__global__ __launch_bounds__(256) void k0_prep(
    const float* __restrict__ conv_w, const float* __restrict__ conv_b,
    const float* __restrict__ bn_s, const float* __restrict__ bn_o,
    const float* __restrict__ bn_m, const float* __restrict__ bn_v,
    char* __restrict__ ws)
{
  int t = blockIdx.x * 256 + threadIdx.x;              // 0..262143
  ((float*)(ws + WS_M1))[t] = 0.f;                     // zero m1+m2 (2*2*65536 f32)
  int f = t >> 16, rem = t & 65535;
  int cin = rem >> 8, cout = rem & 255;
  ((short*)(ws + WS_WT))[f*65536 + cout*256 + cin] = f2bf(conv_w[t]);
  if (t < 1024) {
    float alpha = bn_s[t] * rsqrtf(bn_v[t] + BN_EPS);
    float beta  = alpha * (conv_b[t] - bn_m[t]) + bn_o[t];
    float* ab = (float*)(ws + WS_AB);
    ab[t] = alpha; ab[1024 + t] = beta;
  }
}

// ---------------- k1: 4 fused conv+BN+ReLU branches ---------------------------
// 64 rows/block. A-fragments in REGISTERS for the whole kernel (af[2][8],
// static-indexed). B double-buffered in LDS (2 x 16KB, 32-cout tiles) via
// global_load_lds w=16 with inverse-swizzled source (rule #21). One barrier
// per nt; stage(nt+1) issued at loop top, drained by end-of-nt barrier ->
// L2 latency hidden under k-loop + epilogue. Direct 8B global stores
// (swapped-operand MFMA: lane owns 4 consecutive couts). Zero repack LDS.
__global__ __launch_bounds__(256, 3) void k1_branches(
    const float* __restrict__ x, char* __restrict__ ws)
{
  __shared__ short Bs[2][32 * 256];   // 2 x 16KB

  const int tid = threadIdx.x;
  const int m0  = blockIdx.x * 64;
  const int lane = tid & 63, wid = tid >> 6;
  const int wm = wid >> 1, wn = wid & 1;        // 2 m-halves x 2 cout-halves
  const int lr = lane & 15, lg = lane >> 4;

  const short* Wt = (const short*)(ws + WS_WT);
  const float* ab = (const float*)(ws + WS_AB);

  // ---- issue B stage for nt=0 first (in flight during A gather/convert)
  #pragma unroll
  for (int i = 0; i < 4; ++i) {
    int slot = i * 256 + tid;                  // 1024 16B slots
    int cout = slot >> 5, u = slot & 31;
    int usrc = u ^ ((cout & 7) << 2);
    __builtin_amdgcn_global_load_lds(
        (const __attribute__((address_space(1))) void*)(Wt + cout * 256 + usrc * 8),
        (__attribute__((address_space(3))) void*)(Bs[0] + (i * 256 + wid * 64) * 8),
        16, 0, 0);
  }

  // ---- gather A fragments into registers: af[mi][k0] = x[m][k0*32+lg*8 ..+7]
  s16x8 af[2][8];
  #pragma unroll
  for (int mi = 0; mi < 2; ++mi) {
    const float* xr = x + (size_t)(m0 + wm*32 + mi*16 + lr) * 256 + lg * 8;
    #pragma unroll
    for (int k0 = 0; k0 < 8; ++k0) {
      const float4 v0 = *(const float4*)(xr + k0*32);
      const float4 v1 = *(const float4*)(xr + k0*32 + 4);
      s16x8 t;
      t[0]=f2bf(v0.x); t[1]=f2bf(v0.y); t[2]=f2bf(v0.z); t[3]=f2bf(v0.w);
      t[4]=f2bf(v1.x); t[5]=f2bf(v1.y); t[6]=f2bf(v1.z); t[7]=f2bf(v1.w);
      af[mi][k0] = t;
    }
  }

  __syncthreads();                             // Bs[0] staged

  for (int nt = 0; nt < 32; ++nt) {
    const int f  = nt >> 3;
    const int c0 = (nt & 7) * 32;
    const short* BsCur = Bs[nt & 1];

    // ---- issue next tile's stage into the other buffer (drained by barrier)
    if (nt < 31) {
      const int ntn = nt + 1;
      const short* Wf = Wt + (ntn >> 3) * 65536 + ((ntn & 7) * 32) * 256;
      short* BsNxt = Bs[ntn & 1];
      #pragma unroll
      for (int i = 0; i < 4; ++i) {
        int slot = i * 256 + tid;
        int cout = slot >> 5, u = slot & 31;
        int usrc = u ^ ((cout & 7) << 2);
        __builtin_amdgcn_global_load_lds(
            (const __attribute__((address_space(1))) void*)(Wf + cout * 256 + usrc * 8),
            (__attribute__((address_space(3))) void*)(BsNxt + (i * 256 + wid * 64) * 8),
            16, 0, 0);
      }
    }

    // ---- k-loop: 8 LDS b128 reads + 16 MFMA, no barriers
    f32x4 acc[2];
    { f32x4 z = {0.f,0.f,0.f,0.f}; acc[0] = z; acc[1] = z; }
    #pragma unroll
    for (int k0 = 0; k0 < 8; ++k0) {
      const int ua = k0 * 4 + lg;
      const int c  = wn * 16 + lr;
      const int uu = ua ^ ((c & 7) << 2);
      const s16x8 bf = *(const s16x8*)&BsCur[c * 256 + uu * 8];
      acc[0] = __builtin_amdgcn_mfma_f32_16x16x32_bf16(bf, af[0][k0], acc[0], 0, 0, 0);
      acc[1] = __builtin_amdgcn_mfma_f32_16x16x32_bf16(bf, af[1][k0], acc[1], 0, 0, 0);
    }

    // ---- epilogue: BN affine + ReLU -> direct 8B stores
    // D = W·A^T: m = m0+wm*32+mi*16+lr, cout = c0+wn*16+lg*4+ii
    const int c4b = c0 + wn*16 + lg*4;
    const f32x4 al = *(const f32x4*)&ab[f*256 + c4b];
    const f32x4 be = *(const f32x4*)&ab[1024 + f*256 + c4b];
    short* Yf = (short*)(ws + (size_t)f * SZ_BR);
    #pragma unroll
    for (int mi = 0; mi < 2; ++mi) {
      const int m = m0 + wm*32 + mi*16 + lr;
      s16x4 s;
      #pragma unroll
      for (int ii = 0; ii < 4; ++ii) {
        float yv = al[ii] * acc[mi][ii] + be[ii];
        yv = yv > 0.f ? yv : 0.f;
        s[ii] = f2bf(yv);
      }
      *(s16x4*)&Yf[(size_t)m * 256 + c4b] = s;
    }

    __syncthreads();   // drains stage(nt+1) + guards buffer reuse
  }
}

// ---------------- k2: m1 = K*Q^T, m2 = K*J^T (split-K, atomic accumulate) -----
__global__ __launch_bounds__(256, 2) void k2_m1m2(char* __restrict__ ws)
{
  __shared__ short Ks[128][88], Qs[128][88], Js[128][88];  // stride 176B

  const int tid = threadIdx.x;
  const int chunk = blockIdx.x;                 // 32 chunks of 1024 n
  const int ti = blockIdx.y >> 1, tj = blockIdx.y & 1;
  const int b  = blockIdx.z;
  const size_t boff = (size_t)b * NVOX * CC;
  const short* Qm = (const short*)(ws + WS_Q) + boff;
  const short* Km = (const short*)(ws + WS_K) + boff;
  const short* Jm = (const short*)(ws + WS_J) + boff;

  const int lane = tid & 63, wid = tid >> 6;
  const int wm = wid >> 1, wn = wid & 1;
  const int lr = lane & 15, lg = lane >> 4;

  f32x4 accq[4][4], accj[4][4];
  #pragma unroll
  for (int a = 0; a < 4; ++a)
    #pragma unroll
    for (int c = 0; c < 4; ++c) { f32x4 z = {0.f,0.f,0.f,0.f}; accq[a][c] = z; accj[a][c] = z; }

  const int nstart = chunk * 1024;
  for (int n0 = nstart; n0 < nstart + 1024; n0 += 64) {
    __syncthreads();
    #pragma unroll
    for (int it = 0; it < 4; ++it) {           // 1024 short8 units per tile
      int idx = tid + 256 * it;
      int r = idx >> 3, n8 = (idx & 7) << 3;
      *(s16x8*)&Ks[r][n8] = *(const s16x8*)&Km[(size_t)(ti*128 + r)*NVOX + n0 + n8];
      *(s16x8*)&Qs[r][n8] = *(const s16x8*)&Qm[(size_t)(tj*128 + r)*NVOX + n0 + n8];
      *(s16x8*)&Js[r][n8] = *(const s16x8*)&Jm[(size_t)(tj*128 + r)*NVOX + n0 + n8];
    }
    __syncthreads();
    #pragma unroll
    for (int ks = 0; ks < 2; ++ks) {
      s16x8 a[4], bq[4], bj[4];
      #pragma unroll
      for (int mi = 0; mi < 4; ++mi)
        a[mi] = *(const s16x8*)&Ks[wm*64 + mi*16 + lr][ks*32 + lg*8];
      #pragma unroll
      for (int nj = 0; nj < 4; ++nj) {
        bq[nj] = *(const s16x8*)&Qs[wn*64 + nj*16 + lr][ks*32 + lg*8];
        bj[nj] = *(const s16x8*)&Js[wn*64 + nj*16 + lr][ks*32 + lg*8];
      }
      #pragma unroll
      for (int mi = 0; mi < 4; ++mi)
        #pragma unroll
        for (int nj = 0; nj < 4; ++nj) {
          accq[mi][nj] = __builtin_amdgcn_mfma_f32_16x16x32_bf16(a[mi], bq[nj], accq[mi][nj], 0,0,0);
          accj[mi][nj] = __builtin_amdgcn_mfma_f32_16x16x32_bf16(a[mi], bj[nj], accj[mi][nj], 0,0,0);
        }
    }
  }
  float* m1 = (float*)(ws + WS_M1) + (size_t)b * CC * CC;
  float* m2 = (float*)(ws + WS_M2) + (size_t)b * CC * CC;
  #pragma unroll
  for (int mi = 0; mi < 4; ++mi)
    #pragma unroll
    for (int nj = 0; nj < 4; ++nj)
      #pragma unroll
      for (int ii = 0; ii < 4; ++ii) {
        int i = ti*128 + wm*64 + mi*16 + lg*4 + ii;
        int j = tj*128 + wn*64 + nj*16 + lr;
        atomicAdd(&m1[i*256 + j], accq[mi][nj][ii]);
        atomicAdd(&m2[i*256 + j], accj[mi][nj][ii]);
      }
}

// ---------------- k3: affinity = sigmoid(m1 @ m2) -> bf16 ---------------------
__global__ __launch_bounds__(256) void k3_aff(char* __restrict__ ws)
{
  const int j = threadIdx.x;
  const int i = blockIdx.x & 255;
  const int b = blockIdx.x >> 8;
  const float* m1 = (const float*)(ws + WS_M1) + (size_t)b * CC * CC;
  const float* m2 = (const float*)(ws + WS_M2) + (size_t)b * CC * CC;
  float z = 0.f;
  #pragma unroll 8
  for (int k = 0; k < 256; ++k)
    z = fmaf(m1[i*256 + k], m2[k*256 + j], z);
  float a = 1.f / (1.f + expf(-z));
  ((short*)(ws + WS_AFF))[(size_t)b*CC*CC + i*256 + j] = f2bf(a);
}

// ---------------- k4: out = gamma * (affinity @ V) + x ------------------------
// 512 threads / 8 waves (4i x 2n), block = 256i x 128n, no i-split (V read once).
// Swapped MFMA operands: mfma(bv, af) -> lane owns 4 consecutive n ->
// pure float4 epilogue (x read + out write), no repack LDS needed.
__global__ __launch_bounds__(512, 4) void k4_out(
    const float* __restrict__ x, const float* __restrict__ gamma_p,
    char* __restrict__ ws, float* __restrict__ out)
{
  __shared__ short affS[256][72];  // rows i, 64-c chunk
  __shared__ short Vs[128][72];    // rows n, 64-c chunk (transposed stage)

  const int tid = threadIdx.x;
  const int n0 = blockIdx.x * 128;
  const int b  = blockIdx.y;
  const float gamma = gamma_p[0];
  const short* aff = (const short*)(ws + WS_AFF) + (size_t)b * CC * CC;
  const short* Vm  = (const short*)(ws + WS_V) + (size_t)b * NVOX * CC;  // V_matrix [c][n]

  const int lane = tid & 63, wid = tid >> 6;
  const int wi = wid >> 1, wn = wid & 1;        // 4 i-tiles x 2 n-tiles
  const int lr = lane & 15, lg = lane >> 4;

  f32x4 acc[4][4];
  #pragma unroll
  for (int a = 0; a < 4; ++a)
    #pragma unroll
    for (int c = 0; c < 4; ++c) { f32x4 z = {0.f,0.f,0.f,0.f}; acc[a][c] = z; }

  for (int c0 = 0; c0 < 256; c0 += 64) {
    __syncthreads();                            // prev step's reads complete
    #pragma unroll
    for (int it = 0; it < 4; ++it) {            // affS: 2048 s16x8 units
      int idx = tid + 512 * it;
      int r = idx >> 3, c8 = (idx & 7) << 3;
      *(s16x8*)&affS[r][c8] = *(const s16x8*)&aff[(size_t)r * 256 + c0 + c8];
    }
    #pragma unroll
    for (int it = 0; it < 2; ++it) {            // Vs: 1024 units, transpose
      int idx = tid + 512 * it;
      int t15 = idx & 15;
      int cc = idx >> 4, n8 = t15 << 3;
      s16x8 v = *(const s16x8*)&Vm[(size_t)(c0 + cc) * NVOX + n0 + n8];
      #pragma unroll
      for (int uu = 0; uu < 8; ++uu) {          // lane-rotated: spreads banks
        int u = (uu + t15) & 7;
        Vs[n8 + u][cc] = v[u];
      }
    }
    __syncthreads();
    #pragma unroll
    for (int ks = 0; ks < 2; ++ks) {
      s16x8 af[4], bv[4];
      #pragma unroll
      for (int mi = 0; mi < 4; ++mi)
        af[mi] = *(const s16x8*)&affS[wi*64 + mi*16 + lr][ks*32 + lg*8];
      #pragma unroll
      for (int nj = 0; nj < 4; ++nj)
        bv[nj] = *(const s16x8*)&Vs[wn*64 + nj*16 + lr][ks*32 + lg*8];
      #pragma unroll
      for (int mi = 0; mi < 4; ++mi)
        #pragma unroll
        for (int nj = 0; nj < 4; ++nj)
          acc[mi][nj] = __builtin_amdgcn_mfma_f32_16x16x32_bf16(
              bv[nj], af[mi], acc[mi][nj], 0, 0, 0);   // D = V^T·aff^T
    }
  }
  // epilogue: i = wi*64 + mi*16 + lr; n = n0 + wn*64 + nj*16 + lg*4 + ii
  #pragma unroll
  for (int mi = 0; mi < 4; ++mi)
    #pragma unroll
    for (int nj = 0; nj < 4; ++nj) {
      int i = wi*64 + mi*16 + lr;
      int n = n0 + wn*64 + nj*16 + lg*4;
      size_t flat = (size_t)b * NVOX * CC + (size_t)i * NVOX + n;
      const float4 xv = *(const float4*)(x + flat);
      float4 o;
      o.x = gamma * acc[mi][nj][0] + xv.x;
      o.y = gamma * acc[mi][nj][1] + xv.y;
      o.z = gamma * acc[mi][nj][2] + xv.z;
      o.w = gamma * acc[mi][nj][3] + xv.w;
      *(float4*)(out + flat) = o;
    }
}

// ---------------- launcher ----------------------------------------------------
extern "C" void kernel_launch(void* const* d_in, const int* in_sizes, int n_in,
                              void* d_out, int out_size, void* d_ws, size_t ws_size,
                              hipStream_t stream)
{
  const float* x      = (const float*)d_in[0];
  const float* conv_w = (const float*)d_in[1];
  const float* conv_b = (const float*)d_in[2];
  const float* bn_s   = (const float*)d_in[3];
  const float* bn_o   = (const float*)d_in[4];
  const float* bn_m   = (const float*)d_in[5];
  const float* bn_v   = (const float*)d_in[6];
  const float* gamma  = (const float*)d_in[7];
  char*  ws  = (char*)d_ws;
  float* out = (float*)d_out;

  k0_prep    <<<1024, 256, 0, stream>>>(conv_w, conv_b, bn_s, bn_o, bn_m, bn_v, ws);
  k1_branches<<<1024, 256, 0, stream>>>(x, ws);
  k2_m1m2    <<<dim3(32, 4, 2), 256, 0, stream>>>(ws);
  k3_aff     <<<512, 256, 0, stream>>>(ws);
  k4_out     <<<dim3(256, 2), 512, 0, stream>>>(x, gamma, ws, out);
}

// Round 7
// 198.049 us; speedup vs baseline: 1.0074x; 1.0074x over previous
//
#include <hip/hip_runtime.h>
#include <math.h>

typedef __attribute__((ext_vector_type(4))) float  f32x4;
typedef __attribute__((ext_vector_type(8))) short  s16x8;
typedef __attribute__((ext_vector_type(4))) short  s16x4;

#define BN_EPS 1e-3f

static constexpr int    CC    = 256;
static constexpr int    NVOX  = 32768;
static constexpr int    BATCH = 2;
static constexpr int    MTOT  = BATCH * NVOX;              // 65536 rows
static constexpr size_t ELEM_BR = (size_t)MTOT * CC;       // 16,777,216 per branch
static constexpr size_t SZ_BR   = ELEM_BR * 2;             // bf16 bytes
// workspace layout
static constexpr size_t WS_Q   = 0;
static constexpr size_t WS_K   = WS_Q  + SZ_BR;
static constexpr size_t WS_J   = WS_K  + SZ_BR;
static constexpr size_t WS_V   = WS_J  + SZ_BR;
static constexpr size_t WS_M1  = WS_V  + SZ_BR;                       // f32 [2][256][256]
static constexpr size_t WS_M2  = WS_M1 + (size_t)BATCH*CC*CC*4;
static constexpr size_t WS_AFF = WS_M2 + (size_t)BATCH*CC*CC*4;       // bf16 [2][256][256]
static constexpr size_t WS_WT  = WS_AFF + (size_t)BATCH*CC*CC*2;      // bf16 Wt[4][cout][cin]
static constexpr size_t WS_AB  = WS_WT + (size_t)4*CC*CC*2;           // f32 alpha[1024], beta[1024]

__device__ __forceinline__ short f2bf(float f) {
  union { float f; unsigned u; } v; v.f = f;
  unsigned u = v.u + 0x7FFFu + ((v.u >> 16) & 1u);   // RNE
  return (short)(u >> 16);
}

// ---------------- k0: prep — transpose weights to bf16, fold BN, zero m1/m2 ----
__global__ __launch_bounds__(256) void k0_prep(
    const float* __restrict__ conv_w, const float* __restrict__ conv_b,
    const float* __restrict__ bn_s, const float* __restrict__ bn_o,
    const float* __restrict__ bn_m, const float* __restrict__ bn_v,
    char* __restrict__ ws)
{
  int t = blockIdx.x * 256 + threadIdx.x;              // 0..262143
  ((float*)(ws + WS_M1))[t] = 0.f;                     // zero m1+m2 (2*2*65536 f32)
  int f = t >> 16, rem = t & 65535;
  int cin = rem >> 8, cout = rem & 255;
  ((short*)(ws + WS_WT))[f*65536 + cout*256 + cin] = f2bf(conv_w[t]);
  if (t < 1024) {
    float alpha = bn_s[t] * rsqrtf(bn_v[t] + BN_EPS);
    float beta  = alpha * (conv_b[t] - bn_m[t]) + bn_o[t];
    float* ab = (float*)(ws + WS_AB);
    ab[t] = alpha; ab[1024 + t] = beta;
  }
}

// ---------------- k1: 4 fused conv+BN+ReLU branches (round-4 structure, 80us) --
__global__ __launch_bounds__(256, 2) void k1_branches(
    const float* __restrict__ x, char* __restrict__ ws)
{
  __shared__ short As[64 * 256];
  __shared__ short Bs[64 * 256];
  __shared__ short Rs[64][72];     // repack (row stride 144B = 9 x 16B)

  const int tid = threadIdx.x;
  const int m0  = blockIdx.x * 64;
  const int lane = tid & 63, wid = tid >> 6;
  const int wm = wid >> 1, wn = wid & 1;        // 2x2 waves over 64x64 tile
  const int lr = lane & 15, lg = lane >> 4;

  const short* Wt = (const short*)(ws + WS_WT);
  const float* ab = (const float*)(ws + WS_AB);

  // ---- stage A: 64x256 f32 -> bf16, swizzled
  #pragma unroll
  for (int it = 0; it < 16; ++it) {
    int idx = tid + 256 * it;                  // 4096 float4 units
    int r = idx >> 6, c4 = (idx & 63) << 2;    // c4: short index (mult of 4)
    const float4 v = *(const float4*)(x + (size_t)(m0 + r) * 256 + c4);
    s16x4 s; s[0]=f2bf(v.x); s[1]=f2bf(v.y); s[2]=f2bf(v.z); s[3]=f2bf(v.w);
    int u = c4 >> 3;                           // 16B unit 0..31
    int swz = ((u ^ ((r & 7) << 2)) << 3) | (c4 & 7);
    *(s16x4*)&As[r * 256 + swz] = s;
  }

  // ---- stage Bs for nt=0 (overlaps A staging)
  {
    const short* Wf = Wt;                      // f=0, c0=0
    #pragma unroll
    for (int i = 0; i < 8; ++i) {
      int slot = i * 256 + tid;                // 16B slots 0..2047
      int cout = slot >> 5, u = slot & 31;
      int usrc = u ^ ((cout & 7) << 2);
      const short* src = Wf + cout * 256 + usrc * 8;
      short* dst = Bs + (size_t)(i * 256 + wid * 64) * 8;   // wave-uniform
      __builtin_amdgcn_global_load_lds(
          (const __attribute__((address_space(1))) void*)src,
          (__attribute__((address_space(3))) void*)dst, 16, 0, 0);
    }
  }

  __syncthreads();                             // As + Bs(0) ready

  for (int nt = 0; nt < 16; ++nt) {
    const int f  = nt >> 2;
    const int c0 = (nt & 3) * 64;

    // ---- k-loop: pure LDS reads + MFMA, zero barriers
    f32x4 acc[2][2];
    #pragma unroll
    for (int a = 0; a < 2; ++a)
      #pragma unroll
      for (int b = 0; b < 2; ++b) { f32x4 z = {0.f,0.f,0.f,0.f}; acc[a][b] = z; }

    #pragma unroll
    for (int k0 = 0; k0 < 8; ++k0) {
      const int ua = k0 * 4 + lg;              // logical 16B unit in row
      s16x8 af[2], bf[2];
      #pragma unroll
      for (int mi = 0; mi < 2; ++mi) {
        int r = wm*32 + mi*16 + lr;
        int uu = ua ^ ((r & 7) << 2);
        af[mi] = *(const s16x8*)&As[r * 256 + uu * 8];
      }
      #pragma unroll
      for (int nj = 0; nj < 2; ++nj) {
        int c = wn*32 + nj*16 + lr;
        int uu = ua ^ ((c & 7) << 2);
        bf[nj] = *(const s16x8*)&Bs[c * 256 + uu * 8];
      }
      #pragma unroll
      for (int mi = 0; mi < 2; ++mi)
        #pragma unroll
        for (int nj = 0; nj < 2; ++nj)
          acc[mi][nj] = __builtin_amdgcn_mfma_f32_16x16x32_bf16(
              bf[nj], af[mi], acc[mi][nj], 0, 0, 0);   // D = W·A^T
    }

    __syncthreads();                           // barrier_A: all Bs reads done

    // ---- issue next nt's B stage early; latency hides under epilogue
    if (nt < 15) {
      const int fn  = (nt + 1) >> 2;
      const int c0n = ((nt + 1) & 3) * 64;
      const short* Wf = Wt + fn * 65536 + c0n * 256;
      #pragma unroll
      for (int i = 0; i < 8; ++i) {
        int slot = i * 256 + tid;
        int cout = slot >> 5, u = slot & 31;
        int usrc = u ^ ((cout & 7) << 2);
        const short* src = Wf + cout * 256 + usrc * 8;
        short* dst = Bs + (size_t)(i * 256 + wid * 64) * 8;
        __builtin_amdgcn_global_load_lds(
            (const __attribute__((address_space(1))) void*)src,
            (__attribute__((address_space(3))) void*)dst, 16, 0, 0);
      }
    }

    // ---- epilogue: BN affine + ReLU -> Rs
    #pragma unroll
    for (int nj = 0; nj < 2; ++nj) {
      int c4b = c0 + wn*32 + nj*16 + lg*4;
      const f32x4 al = *(const f32x4*)&ab[f*256 + c4b];
      const f32x4 be = *(const f32x4*)&ab[1024 + f*256 + c4b];
      #pragma unroll
      for (int mi = 0; mi < 2; ++mi) {
        s16x4 s;
        #pragma unroll
        for (int ii = 0; ii < 4; ++ii) {
          float yv = al[ii] * acc[mi][nj][ii] + be[ii];
          yv = yv > 0.f ? yv : 0.f;
          s[ii] = f2bf(yv);
        }
        *(s16x4*)&Rs[wm*32 + mi*16 + lr][wn*32 + nj*16 + lg*4] = s;
      }
    }

    __syncthreads();                           // barrier_B: stage drained + Rs visible

    // ---- Rs -> global (16B coalesced)
    short* Yf = (short*)(ws + (size_t)f * SZ_BR);
    #pragma unroll
    for (int it = 0; it < 2; ++it) {
      int idx = tid + 256 * it;                // 512 s16x8 units
      int r = idx >> 3, c8 = (idx & 7) << 3;
      *(s16x8*)&Yf[(size_t)(m0 + r) * 256 + c0 + c8] = *(const s16x8*)&Rs[r][c8];
    }
  }
}

// ---------------- k2: m1 = K*Q^T, m2 = K*J^T (split-K, atomic accumulate) -----
// NEW: 64 chunks (512 blocks, 2/CU, 8 waves/CU), global_load_lds staging with
// inverse-swizzled source (u^(r&7), rule #21), linear [128][64] tiles (48KB),
// conflict-free reads by bank math. 2 barriers / 64-n tile, 128 MFMA between.
__global__ __launch_bounds__(256, 2) void k2_m1m2(char* __restrict__ ws)
{
  __shared__ short Ks[128 * 64];
  __shared__ short Qs[128 * 64];
  __shared__ short Js[128 * 64];

  const int tid = threadIdx.x;
  const int chunk = blockIdx.x;                 // 64 chunks of 512 n
  const int ti = blockIdx.y >> 1, tj = blockIdx.y & 1;
  const int b  = blockIdx.z;
  const size_t boff = (size_t)b * NVOX * CC;
  const short* Km = (const short*)(ws + WS_K) + boff + (size_t)(ti*128) * NVOX;
  const short* Qm = (const short*)(ws + WS_Q) + boff + (size_t)(tj*128) * NVOX;
  const short* Jm = (const short*)(ws + WS_J) + boff + (size_t)(tj*128) * NVOX;

  const int lane = tid & 63, wid = tid >> 6;
  const int wm = wid >> 1, wn = wid & 1;
  const int lr = lane & 15, lg = lane >> 4;

  f32x4 accq[4][4], accj[4][4];
  #pragma unroll
  for (int a = 0; a < 4; ++a)
    #pragma unroll
    for (int c = 0; c < 4; ++c) { f32x4 z = {0.f,0.f,0.f,0.f}; accq[a][c] = z; accj[a][c] = z; }

  for (int t = 0; t < 8; ++t) {
    const int n0 = chunk * 512 + t * 64;
    __syncthreads();                           // prev tile's reads complete
    // stage K/Q/J 128x64 each; LDS linear, source inverse-swizzled
    #pragma unroll
    for (int i = 0; i < 4; ++i) {
      int slot = i * 256 + tid;                // 1024 16B units per matrix
      int r = slot >> 3, u = slot & 7;
      int usrc = u ^ (r & 7);
      const size_t so = (size_t)r * NVOX + n0 + usrc * 8;
      short* dK = Ks + (size_t)(i * 256 + wid * 64) * 8;
      short* dQ = Qs + (size_t)(i * 256 + wid * 64) * 8;
      short* dJ = Js + (size_t)(i * 256 + wid * 64) * 8;
      __builtin_amdgcn_global_load_lds(
          (const __attribute__((address_space(1))) void*)(Km + so),
          (__attribute__((address_space(3))) void*)dK, 16, 0, 0);
      __builtin_amdgcn_global_load_lds(
          (const __attribute__((address_space(1))) void*)(Qm + so),
          (__attribute__((address_space(3))) void*)dQ, 16, 0, 0);
      __builtin_amdgcn_global_load_lds(
          (const __attribute__((address_space(1))) void*)(Jm + so),
          (__attribute__((address_space(3))) void*)dJ, 16, 0, 0);
    }
    __syncthreads();                           // stage drained + visible
    #pragma unroll
    for (int ks = 0; ks < 2; ++ks) {
      const int ua = ks * 4 + lg;              // logical 16B unit in 64-n row
      s16x8 a[4], bq[4], bj[4];
      #pragma unroll
      for (int mi = 0; mi < 4; ++mi) {
        int r = wm*64 + mi*16 + lr;
        a[mi] = *(const s16x8*)&Ks[r * 64 + (ua ^ (r & 7)) * 8];
      }
      #pragma unroll
      for (int nj = 0; nj < 4; ++nj) {
        int r = wn*64 + nj*16 + lr;
        bq[nj] = *(const s16x8*)&Qs[r * 64 + (ua ^ (r & 7)) * 8];
        bj[nj] = *(const s16x8*)&Js[r * 64 + (ua ^ (r & 7)) * 8];
      }
      #pragma unroll
      for (int mi = 0; mi < 4; ++mi)
        #pragma unroll
        for (int nj = 0; nj < 4; ++nj) {
          accq[mi][nj] = __builtin_amdgcn_mfma_f32_16x16x32_bf16(a[mi], bq[nj], accq[mi][nj], 0,0,0);
          accj[mi][nj] = __builtin_amdgcn_mfma_f32_16x16x32_bf16(a[mi], bj[nj], accj[mi][nj], 0,0,0);
        }
    }
  }
  float* m1 = (float*)(ws + WS_M1) + (size_t)b * CC * CC;
  float* m2 = (float*)(ws + WS_M2) + (size_t)b * CC * CC;
  #pragma unroll
  for (int mi = 0; mi < 4; ++mi)
    #pragma unroll
    for (int nj = 0; nj < 4; ++nj)
      #pragma unroll
      for (int ii = 0; ii < 4; ++ii) {
        int i = ti*128 + wm*64 + mi*16 + lg*4 + ii;
        int j = tj*128 + wn*64 + nj*16 + lr;
        atomicAdd(&m1[i*256 + j], accq[mi][nj][ii]);
        atomicAdd(&m2[i*256 + j], accj[mi][nj][ii]);
      }
}

// ---------------- k3: affinity = sigmoid(m1 @ m2) -> bf16 ---------------------
__global__ __launch_bounds__(256) void k3_aff(char* __restrict__ ws)
{
  const int j = threadIdx.x;
  const int i = blockIdx.x & 255;
  const int b = blockIdx.x >> 8;
  const float* m1 = (const float*)(ws + WS_M1) + (size_t)b * CC * CC;
  const float* m2 = (const float*)(ws + WS_M2) + (size_t)b * CC * CC;
  float z = 0.f;
  #pragma unroll 8
  for (int k = 0; k < 256; ++k)
    z = fmaf(m1[i*256 + k], m2[k*256 + j], z);
  float a = 1.f / (1.f + expf(-z));
  ((short*)(ws + WS_AFF))[(size_t)b*CC*CC + i*256 + j] = f2bf(a);
}

// ---------------- k4: out = gamma * (affinity @ V) + x ------------------------
__global__ __launch_bounds__(512, 4) void k4_out(
    const float* __restrict__ x, const float* __restrict__ gamma_p,
    char* __restrict__ ws, float* __restrict__ out)
{
  __shared__ short affS[256][72];  // rows i, 64-c chunk
  __shared__ short Vs[128][72];    // rows n, 64-c chunk (transposed stage)

  const int tid = threadIdx.x;
  const int n0 = blockIdx.x * 128;
  const int b  = blockIdx.y;
  const float gamma = gamma_p[0];
  const short* aff = (const short*)(ws + WS_AFF) + (size_t)b * CC * CC;
  const short* Vm  = (const short*)(ws + WS_V) + (size_t)b * NVOX * CC;  // V_matrix [c][n]

  const int lane = tid & 63, wid = tid >> 6;
  const int wi = wid >> 1, wn = wid & 1;        // 4 i-tiles x 2 n-tiles
  const int lr = lane & 15, lg = lane >> 4;

  f32x4 acc[4][4];
  #pragma unroll
  for (int a = 0; a < 4; ++a)
    #pragma unroll
    for (int c = 0; c < 4; ++c) { f32x4 z = {0.f,0.f,0.f,0.f}; acc[a][c] = z; }

  for (int c0 = 0; c0 < 256; c0 += 64) {
    __syncthreads();                            // prev step's reads complete
    #pragma unroll
    for (int it = 0; it < 4; ++it) {            // affS: 2048 s16x8 units
      int idx = tid + 512 * it;
      int r = idx >> 3, c8 = (idx & 7) << 3;
      *(s16x8*)&affS[r][c8] = *(const s16x8*)&aff[(size_t)r * 256 + c0 + c8];
    }
    #pragma unroll
    for (int it = 0; it < 2; ++it) {            // Vs: 1024 units, transpose
      int idx = tid + 512 * it;
      int t15 = idx & 15;
      int cc = idx >> 4, n8 = t15 << 3;
      s16x8 v = *(const s16x8*)&Vm[(size_t)(c0 + cc) * NVOX + n0 + n8];
      #pragma unroll
      for (int uu = 0; uu < 8; ++uu) {          // lane-rotated: spreads banks
        int u = (uu + t15) & 7;
        Vs[n8 + u][cc] = v[u];
      }
    }
    __syncthreads();
    #pragma unroll
    for (int ks = 0; ks < 2; ++ks) {
      s16x8 af[4], bv[4];
      #pragma unroll
      for (int mi = 0; mi < 4; ++mi)
        af[mi] = *(const s16x8*)&affS[wi*64 + mi*16 + lr][ks*32 + lg*8];
      #pragma unroll
      for (int nj = 0; nj < 4; ++nj)
        bv[nj] = *(const s16x8*)&Vs[wn*64 + nj*16 + lr][ks*32 + lg*8];
      #pragma unroll
      for (int mi = 0; mi < 4; ++mi)
        #pragma unroll
        for (int nj = 0; nj < 4; ++nj)
          acc[mi][nj] = __builtin_amdgcn_mfma_f32_16x16x32_bf16(
              bv[nj], af[mi], acc[mi][nj], 0, 0, 0);   // D = V^T·aff^T
    }
  }
  // epilogue: i = wi*64 + mi*16 + lr; n = n0 + wn*64 + nj*16 + lg*4 + ii
  #pragma unroll
  for (int mi = 0; mi < 4; ++mi)
    #pragma unroll
    for (int nj = 0; nj < 4; ++nj) {
      int i = wi*64 + mi*16 + lr;
      int n = n0 + wn*64 + nj*16 + lg*4;
      size_t flat = (size_t)b * NVOX * CC + (size_t)i * NVOX + n;
      const float4 xv = *(const float4*)(x + flat);
      float4 o;
      o.x = gamma * acc[mi][nj][0] + xv.x;
      o.y = gamma * acc[mi][nj][1] + xv.y;
      o.z = gamma * acc[mi][nj][2] + xv.z;
      o.w = gamma * acc[mi][nj][3] + xv.w;
      *(float4*)(out + flat) = o;
    }
}

// ---------------- launcher ----------------------------------------------------
extern "C" void kernel_launch(void* const* d_in, const int* in_sizes, int n_in,
                              void* d_out, int out_size, void* d_ws, size_t ws_size,
                              hipStream_t stream)
{
  const float* x      = (const float*)d_in[0];
  const float* conv_w = (const float*)d_in[1];
  const float* conv_b = (const float*)d_in[2];
  const float* bn_s   = (const float*)d_in[3];
  const float* bn_o   = (const float*)d_in[4];
  const float* bn_m   = (const float*)d_in[5];
  const float* bn_v   = (const float*)d_in[6];
  const float* gamma  = (const float*)d_in[7];
  char*  ws  = (char*)d_ws;
  float* out = (float*)d_out;

  k0_prep    <<<1024, 256, 0, stream>>>(conv_w, conv_b, bn_s, bn_o, bn_m, bn_v, ws);
  k1_branches<<<1024, 256, 0, stream>>>(x, ws);
  k2_m1m2    <<<dim3(64, 4, 2), 256, 0, stream>>>(ws);
  k3_aff     <<<512, 256, 0, stream>>>(ws);
  k4_out     <<<dim3(256, 2), 512, 0, stream>>>(x, gamma, ws, out);
}

// Round 8
// 166.568 us; speedup vs baseline: 1.1978x; 1.1890x over previous
//
#include <hip/hip_runtime.h>
#include <math.h>

typedef __attribute__((ext_vector_type(4))) float  f32x4;
typedef __attribute__((ext_vector_type(8))) short  s16x8;
typedef __attribute__((ext_vector_type(4))) short  s16x4;

#define BN_EPS 1e-3f

static constexpr int    CC    = 256;
static constexpr int    NVOX  = 32768;
static constexpr int    BATCH = 2;
static constexpr int    MTOT  = BATCH * NVOX;              // 65536 rows
static constexpr size_t ELEM_BR = (size_t)MTOT * CC;       // 16,777,216 per branch
static constexpr size_t SZ_BR   = ELEM_BR * 2;             // bf16 bytes
// workspace layout
static constexpr size_t WS_Q   = 0;
static constexpr size_t WS_K   = WS_Q  + SZ_BR;
static constexpr size_t WS_J   = WS_K  + SZ_BR;
static constexpr size_t WS_V   = WS_J  + SZ_BR;
static constexpr size_t WS_M1  = WS_V  + SZ_BR;                       // f32 [2][256][256]
static constexpr size_t WS_M2  = WS_M1 + (size_t)BATCH*CC*CC*4;
static constexpr size_t WS_AFF = WS_M2 + (size_t)BATCH*CC*CC*4;       // bf16 [2][256][256]
static constexpr size_t WS_WT  = WS_AFF + (size_t)BATCH*CC*CC*2;      // bf16 Wt[4][cout][cin]
static constexpr size_t WS_AB  = WS_WT + (size_t)4*CC*CC*2;           // f32 alpha[1024], beta[1024]
static constexpr size_t WS_P   = WS_AB + 2048*4;                      // bf16 partials [4][64][65536]
static constexpr size_t WS_NEED_PART = WS_P + (size_t)4*64*65536*2;   // ~162 MiB

__device__ __forceinline__ short f2bf(float f) {
  union { float f; unsigned u; } v; v.f = f;
  unsigned u = v.u + 0x7FFFu + ((v.u >> 16) & 1u);   // RNE
  return (short)(u >> 16);
}
__device__ __forceinline__ float bf2f(short s) {
  union { unsigned u; float f; } v; v.u = ((unsigned)(unsigned short)s) << 16;
  return v.f;
}

// ---------------- k0: prep — transpose weights to bf16, fold BN, zero m1/m2 ----
__global__ __launch_bounds__(256) void k0_prep(
    const float* __restrict__ conv_w, const float* __restrict__ conv_b,
    const float* __restrict__ bn_s, const float* __restrict__ bn_o,
    const float* __restrict__ bn_m, const float* __restrict__ bn_v,
    char* __restrict__ ws)
{
  int t = blockIdx.x * 256 + threadIdx.x;              // 0..262143
  ((float*)(ws + WS_M1))[t] = 0.f;                     // zero m1+m2 (2*2*65536 f32)
  int f = t >> 16, rem = t & 65535;
  int cin = rem >> 8, cout = rem & 255;
  ((short*)(ws + WS_WT))[f*65536 + cout*256 + cin] = f2bf(conv_w[t]);
  if (t < 1024) {
    float alpha = bn_s[t] * rsqrtf(bn_v[t] + BN_EPS);
    float beta  = alpha * (conv_b[t] - bn_m[t]) + bn_o[t];
    float* ab = (float*)(ws + WS_AB);
    ab[t] = alpha; ab[1024 + t] = beta;
  }
}

// ---------------- k1: 4 fused conv+BN+ReLU branches (round-4 structure, 80us) --
__global__ __launch_bounds__(256, 2) void k1_branches(
    const float* __restrict__ x, char* __restrict__ ws)
{
  __shared__ short As[64 * 256];
  __shared__ short Bs[64 * 256];
  __shared__ short Rs[64][72];     // repack (row stride 144B = 9 x 16B)

  const int tid = threadIdx.x;
  const int m0  = blockIdx.x * 64;
  const int lane = tid & 63, wid = tid >> 6;
  const int wm = wid >> 1, wn = wid & 1;        // 2x2 waves over 64x64 tile
  const int lr = lane & 15, lg = lane >> 4;

  const short* Wt = (const short*)(ws + WS_WT);
  const float* ab = (const float*)(ws + WS_AB);

  #pragma unroll
  for (int it = 0; it < 16; ++it) {
    int idx = tid + 256 * it;
    int r = idx >> 6, c4 = (idx & 63) << 2;
    const float4 v = *(const float4*)(x + (size_t)(m0 + r) * 256 + c4);
    s16x4 s; s[0]=f2bf(v.x); s[1]=f2bf(v.y); s[2]=f2bf(v.z); s[3]=f2bf(v.w);
    int u = c4 >> 3;
    int swz = ((u ^ ((r & 7) << 2)) << 3) | (c4 & 7);
    *(s16x4*)&As[r * 256 + swz] = s;
  }

  {
    const short* Wf = Wt;
    #pragma unroll
    for (int i = 0; i < 8; ++i) {
      int slot = i * 256 + tid;
      int cout = slot >> 5, u = slot & 31;
      int usrc = u ^ ((cout & 7) << 2);
      const short* src = Wf + cout * 256 + usrc * 8;
      short* dst = Bs + (size_t)(i * 256 + wid * 64) * 8;
      __builtin_amdgcn_global_load_lds(
          (const __attribute__((address_space(1))) void*)src,
          (__attribute__((address_space(3))) void*)dst, 16, 0, 0);
    }
  }

  __syncthreads();

  for (int nt = 0; nt < 16; ++nt) {
    const int f  = nt >> 2;
    const int c0 = (nt & 3) * 64;

    f32x4 acc[2][2];
    #pragma unroll
    for (int a = 0; a < 2; ++a)
      #pragma unroll
      for (int b = 0; b < 2; ++b) { f32x4 z = {0.f,0.f,0.f,0.f}; acc[a][b] = z; }

    #pragma unroll
    for (int k0 = 0; k0 < 8; ++k0) {
      const int ua = k0 * 4 + lg;
      s16x8 af[2], bf[2];
      #pragma unroll
      for (int mi = 0; mi < 2; ++mi) {
        int r = wm*32 + mi*16 + lr;
        int uu = ua ^ ((r & 7) << 2);
        af[mi] = *(const s16x8*)&As[r * 256 + uu * 8];
      }
      #pragma unroll
      for (int nj = 0; nj < 2; ++nj) {
        int c = wn*32 + nj*16 + lr;
        int uu = ua ^ ((c & 7) << 2);
        bf[nj] = *(const s16x8*)&Bs[c * 256 + uu * 8];
      }
      #pragma unroll
      for (int mi = 0; mi < 2; ++mi)
        #pragma unroll
        for (int nj = 0; nj < 2; ++nj)
          acc[mi][nj] = __builtin_amdgcn_mfma_f32_16x16x32_bf16(
              bf[nj], af[mi], acc[mi][nj], 0, 0, 0);   // D = W·A^T
    }

    __syncthreads();                           // barrier_A

    if (nt < 15) {
      const int fn  = (nt + 1) >> 2;
      const int c0n = ((nt + 1) & 3) * 64;
      const short* Wf = Wt + fn * 65536 + c0n * 256;
      #pragma unroll
      for (int i = 0; i < 8; ++i) {
        int slot = i * 256 + tid;
        int cout = slot >> 5, u = slot & 31;
        int usrc = u ^ ((cout & 7) << 2);
        const short* src = Wf + cout * 256 + usrc * 8;
        short* dst = Bs + (size_t)(i * 256 + wid * 64) * 8;
        __builtin_amdgcn_global_load_lds(
            (const __attribute__((address_space(1))) void*)src,
            (__attribute__((address_space(3))) void*)dst, 16, 0, 0);
      }
    }

    #pragma unroll
    for (int nj = 0; nj < 2; ++nj) {
      int c4b = c0 + wn*32 + nj*16 + lg*4;
      const f32x4 al = *(const f32x4*)&ab[f*256 + c4b];
      const f32x4 be = *(const f32x4*)&ab[1024 + f*256 + c4b];
      #pragma unroll
      for (int mi = 0; mi < 2; ++mi) {
        s16x4 s;
        #pragma unroll
        for (int ii = 0; ii < 4; ++ii) {
          float yv = al[ii] * acc[mi][nj][ii] + be[ii];
          yv = yv > 0.f ? yv : 0.f;
          s[ii] = f2bf(yv);
        }
        *(s16x4*)&Rs[wm*32 + mi*16 + lr][wn*32 + nj*16 + lg*4] = s;
      }
    }

    __syncthreads();                           // barrier_B

    short* Yf = (short*)(ws + (size_t)f * SZ_BR);
    #pragma unroll
    for (int it = 0; it < 2; ++it) {
      int idx = tid + 256 * it;
      int r = idx >> 3, c8 = (idx & 7) << 3;
      *(s16x8*)&Yf[(size_t)(m0 + r) * 256 + c0 + c8] = *(const s16x8*)&Rs[r][c8];
    }
  }
}

// ---------------- k2: m1 = K*Q^T, m2 = K*J^T ---------------------------------
// 256 blocks (64 chunks x 2 matrices x 2 batches), 512 threads, full 256x256
// partial per block (acc 128 f32/thread). Double-buffered global_load_lds
// staging (K + Q-or-J, one barrier/tile). PART=1: bf16 partial -> ws (no
// atomics, k25 reduces). PART=0: f32 atomicAdd fallback.
template<int PART>
__global__ __launch_bounds__(512, 2) void k2_m1m2(char* __restrict__ ws)
{
  __shared__ short Ks[2][16384];   // [buf][256 rows x 64 n] 32KB each
  __shared__ short Xs[2][16384];

  const int tid = threadIdx.x;               // 0..511
  const int chunk = blockIdx.x;              // 64 chunks x 512 voxels
  const int mat = blockIdx.y;                // 0: m1 (X=Q), 1: m2 (X=J)
  const int b   = blockIdx.z;
  const size_t boff = (size_t)b * NVOX * CC;
  const short* Km = (const short*)(ws + WS_K) + boff;
  const short* Xm = (const short*)(ws + (mat ? WS_J : WS_Q)) + boff;

  const int lane = tid & 63, wid = tid >> 6;
  const int wm = wid >> 1, wn = wid & 1;     // 4 m-tiles(64 rows) x 2 n-tiles(128 cols)
  const int lr = lane & 15, lg = lane >> 4;

  f32x4 acc[4][8];
  #pragma unroll
  for (int a = 0; a < 4; ++a)
    #pragma unroll
    for (int c = 0; c < 8; ++c) { f32x4 z = {0.f,0.f,0.f,0.f}; acc[a][c] = z; }

  // stage tile 0 into buf 0
  {
    const int n0 = chunk * 512;
    #pragma unroll
    for (int i = 0; i < 4; ++i) {
      int slot = i * 512 + tid;              // 2048 16B-units per matrix tile
      int r = slot >> 3, u = slot & 7;
      int usrc = u ^ (r & 7);
      const size_t so = (size_t)r * NVOX + n0 + usrc * 8;
      short* dK = Ks[0] + (size_t)(i * 512 + wid * 64) * 8;
      short* dX = Xs[0] + (size_t)(i * 512 + wid * 64) * 8;
      __builtin_amdgcn_global_load_lds(
          (const __attribute__((address_space(1))) void*)(Km + so),
          (__attribute__((address_space(3))) void*)dK, 16, 0, 0);
      __builtin_amdgcn_global_load_lds(
          (const __attribute__((address_space(1))) void*)(Xm + so),
          (__attribute__((address_space(3))) void*)dX, 16, 0, 0);
    }
  }
  __syncthreads();

  for (int t = 0; t < 8; ++t) {
    const int cur = t & 1;
    // ---- issue stage(t+1) into other buffer; drained by end-of-iter barrier
    if (t < 7) {
      const int n0n = chunk * 512 + (t + 1) * 64;
      const int nxt = cur ^ 1;
      #pragma unroll
      for (int i = 0; i < 4; ++i) {
        int slot = i * 512 + tid;
        int r = slot >> 3, u = slot & 7;
        int usrc = u ^ (r & 7);
        const size_t so = (size_t)r * NVOX + n0n + usrc * 8;
        short* dK = Ks[nxt] + (size_t)(i * 512 + wid * 64) * 8;
        short* dX = Xs[nxt] + (size_t)(i * 512 + wid * 64) * 8;
        __builtin_amdgcn_global_load_lds(
            (const __attribute__((address_space(1))) void*)(Km + so),
            (__attribute__((address_space(3))) void*)dK, 16, 0, 0);
        __builtin_amdgcn_global_load_lds(
            (const __attribute__((address_space(1))) void*)(Xm + so),
            (__attribute__((address_space(3))) void*)dX, 16, 0, 0);
      }
    }
    // ---- compute tile t: 64 MFMA + 24 ds_read_b128 per thread
    #pragma unroll
    for (int ks = 0; ks < 2; ++ks) {
      const int ua = ks * 4 + lg;
      s16x8 a[4], xf[8];
      #pragma unroll
      for (int mi = 0; mi < 4; ++mi) {
        int r = wm*64 + mi*16 + lr;
        a[mi] = *(const s16x8*)&Ks[cur][r * 64 + (ua ^ (r & 7)) * 8];
      }
      #pragma unroll
      for (int nj = 0; nj < 8; ++nj) {
        int r = wn*128 + nj*16 + lr;
        xf[nj] = *(const s16x8*)&Xs[cur][r * 64 + (ua ^ (r & 7)) * 8];
      }
      #pragma unroll
      for (int mi = 0; mi < 4; ++mi)
        #pragma unroll
        for (int nj = 0; nj < 8; ++nj)
          acc[mi][nj] = __builtin_amdgcn_mfma_f32_16x16x32_bf16(
              a[mi], xf[nj], acc[mi][nj], 0, 0, 0);  // i rows from K, j cols from X
    }
    __syncthreads();
  }

  // ---- epilogue
  if (PART) {
    short* P = (short*)(ws + WS_P) + ((size_t)((mat*2 + b)*64 + chunk)) * 65536;
    #pragma unroll
    for (int mi = 0; mi < 4; ++mi)
      #pragma unroll
      for (int nj = 0; nj < 8; ++nj) {
        int i = wm*64 + mi*16 + lg*4;
        int j = wn*128 + nj*16 + lr;
        #pragma unroll
        for (int ii = 0; ii < 4; ++ii)
          P[(size_t)(i + ii) * 256 + j] = f2bf(acc[mi][nj][ii]);
      }
  } else {
    float* M = (float*)(ws + (mat ? WS_M2 : WS_M1)) + (size_t)b * CC * CC;
    #pragma unroll
    for (int mi = 0; mi < 4; ++mi)
      #pragma unroll
      for (int nj = 0; nj < 8; ++nj) {
        int i = wm*64 + mi*16 + lg*4;
        int j = wn*128 + nj*16 + lr;
        #pragma unroll
        for (int ii = 0; ii < 4; ++ii)
          atomicAdd(&M[(size_t)(i + ii) * 256 + j], acc[mi][nj][ii]);
      }
  }
}

// ---------------- k25: reduce bf16 partials -> f32 m1/m2 ----------------------
__global__ __launch_bounds__(256) void k25_reduce(char* __restrict__ ws)
{
  int idx = blockIdx.x * 256 + threadIdx.x;   // 0..262143
  int mb = idx >> 16;                         // mat*2 + batch
  int ij = idx & 65535;
  const short* P = (const short*)(ws + WS_P) + ((size_t)mb * 64) * 65536 + ij;
  float s = 0.f;
  #pragma unroll 8
  for (int c = 0; c < 64; ++c)
    s += bf2f(P[(size_t)c * 65536]);
  float* dst = (float*)(ws + ((mb >> 1) ? WS_M2 : WS_M1)) + (size_t)(mb & 1) * 65536 + ij;
  *dst = s;
}

// ---------------- k3: affinity = sigmoid(m1 @ m2) -> bf16 ---------------------
__global__ __launch_bounds__(256) void k3_aff(char* __restrict__ ws)
{
  const int j = threadIdx.x;
  const int i = blockIdx.x & 255;
  const int b = blockIdx.x >> 8;
  const float* m1 = (const float*)(ws + WS_M1) + (size_t)b * CC * CC;
  const float* m2 = (const float*)(ws + WS_M2) + (size_t)b * CC * CC;
  float z = 0.f;
  #pragma unroll 8
  for (int k = 0; k < 256; ++k)
    z = fmaf(m1[i*256 + k], m2[k*256 + j], z);
  float a = 1.f / (1.f + expf(-z));
  ((short*)(ws + WS_AFF))[(size_t)b*CC*CC + i*256 + j] = f2bf(a);
}

// ---------------- k4: out = gamma * (affinity @ V) + x ------------------------
__global__ __launch_bounds__(512, 4) void k4_out(
    const float* __restrict__ x, const float* __restrict__ gamma_p,
    char* __restrict__ ws, float* __restrict__ out)
{
  __shared__ short affS[256][72];  // rows i, 64-c chunk
  __shared__ short Vs[128][72];    // rows n, 64-c chunk (transposed stage)

  const int tid = threadIdx.x;
  const int n0 = blockIdx.x * 128;
  const int b  = blockIdx.y;
  const float gamma = gamma_p[0];
  const short* aff = (const short*)(ws + WS_AFF) + (size_t)b * CC * CC;
  const short* Vm  = (const short*)(ws + WS_V) + (size_t)b * NVOX * CC;

  const int lane = tid & 63, wid = tid >> 6;
  const int wi = wid >> 1, wn = wid & 1;
  const int lr = lane & 15, lg = lane >> 4;

  f32x4 acc[4][4];
  #pragma unroll
  for (int a = 0; a < 4; ++a)
    #pragma unroll
    for (int c = 0; c < 4; ++c) { f32x4 z = {0.f,0.f,0.f,0.f}; acc[a][c] = z; }

  for (int c0 = 0; c0 < 256; c0 += 64) {
    __syncthreads();
    #pragma unroll
    for (int it = 0; it < 4; ++it) {
      int idx = tid + 512 * it;
      int r = idx >> 3, c8 = (idx & 7) << 3;
      *(s16x8*)&affS[r][c8] = *(const s16x8*)&aff[(size_t)r * 256 + c0 + c8];
    }
    #pragma unroll
    for (int it = 0; it < 2; ++it) {
      int idx = tid + 512 * it;
      int t15 = idx & 15;
      int cc = idx >> 4, n8 = t15 << 3;
      s16x8 v = *(const s16x8*)&Vm[(size_t)(c0 + cc) * NVOX + n0 + n8];
      #pragma unroll
      for (int uu = 0; uu < 8; ++uu) {
        int u = (uu + t15) & 7;
        Vs[n8 + u][cc] = v[u];
      }
    }
    __syncthreads();
    #pragma unroll
    for (int ks = 0; ks < 2; ++ks) {
      s16x8 af[4], bv[4];
      #pragma unroll
      for (int mi = 0; mi < 4; ++mi)
        af[mi] = *(const s16x8*)&affS[wi*64 + mi*16 + lr][ks*32 + lg*8];
      #pragma unroll
      for (int nj = 0; nj < 4; ++nj)
        bv[nj] = *(const s16x8*)&Vs[wn*64 + nj*16 + lr][ks*32 + lg*8];
      #pragma unroll
      for (int mi = 0; mi < 4; ++mi)
        #pragma unroll
        for (int nj = 0; nj < 4; ++nj)
          acc[mi][nj] = __builtin_amdgcn_mfma_f32_16x16x32_bf16(
              bv[nj], af[mi], acc[mi][nj], 0, 0, 0);   // D = V^T·aff^T
    }
  }
  #pragma unroll
  for (int mi = 0; mi < 4; ++mi)
    #pragma unroll
    for (int nj = 0; nj < 4; ++nj) {
      int i = wi*64 + mi*16 + lr;
      int n = n0 + wn*64 + nj*16 + lg*4;
      size_t flat = (size_t)b * NVOX * CC + (size_t)i * NVOX + n;
      const float4 xv = *(const float4*)(x + flat);
      float4 o;
      o.x = gamma * acc[mi][nj][0] + xv.x;
      o.y = gamma * acc[mi][nj][1] + xv.y;
      o.z = gamma * acc[mi][nj][2] + xv.z;
      o.w = gamma * acc[mi][nj][3] + xv.w;
      *(float4*)(out + flat) = o;
    }
}

// ---------------- launcher ----------------------------------------------------
extern "C" void kernel_launch(void* const* d_in, const int* in_sizes, int n_in,
                              void* d_out, int out_size, void* d_ws, size_t ws_size,
                              hipStream_t stream)
{
  const float* x      = (const float*)d_in[0];
  const float* conv_w = (const float*)d_in[1];
  const float* conv_b = (const float*)d_in[2];
  const float* bn_s   = (const float*)d_in[3];
  const float* bn_o   = (const float*)d_in[4];
  const float* bn_m   = (const float*)d_in[5];
  const float* bn_v   = (const float*)d_in[6];
  const float* gamma  = (const float*)d_in[7];
  char*  ws  = (char*)d_ws;
  float* out = (float*)d_out;

  const bool part = ws_size >= WS_NEED_PART;

  k0_prep    <<<1024, 256, 0, stream>>>(conv_w, conv_b, bn_s, bn_o, bn_m, bn_v, ws);
  k1_branches<<<1024, 256, 0, stream>>>(x, ws);
  if (part) {
    k2_m1m2<1><<<dim3(64, 2, 2), 512, 0, stream>>>(ws);
    k25_reduce<<<1024, 256, 0, stream>>>(ws);
  } else {
    k2_m1m2<0><<<dim3(64, 2, 2), 512, 0, stream>>>(ws);
  }
  k3_aff     <<<512, 256, 0, stream>>>(ws);
  k4_out     <<<dim3(256, 2), 512, 0, stream>>>(x, gamma, ws, out);
}